// Round 5
// baseline (470.012 us; speedup 1.0000x reference)
//
#include <hip/hip_runtime.h>

#define CAP 64
#define BINSZ 128
#define BINCAP 1792  // Poisson(1536) + 6.5 sigma; overflow prob ~4e-11/bin

typedef short bf16x8 __attribute__((ext_vector_type(8)));
typedef float f32x4 __attribute__((ext_vector_type(4)));
typedef unsigned short u16;
typedef unsigned int u32;

__device__ __forceinline__ u16 f32_to_bf16(float f) {
  u32 b = __float_as_uint(f);
  b += 0x7fffu + ((b >> 16) & 1u);  // round to nearest even
  return (u16)(b >> 16);
}

// ---------------------------------------------------------------------------
// K0: X fp32 -> bf16, packed into d_out lower half (dead until mlp writes).
// ---------------------------------------------------------------------------
__global__ void convert_x_kernel(const float* __restrict__ X,
                                 u16* __restrict__ Xb, int n8) {
  int i = blockIdx.x * blockDim.x + threadIdx.x;
  if (i >= n8) return;
  float4 a = ((const float4*)X)[2 * i];
  float4 b = ((const float4*)X)[2 * i + 1];
  int4 o;
  o.x = (int)((u32)f32_to_bf16(a.x) | ((u32)f32_to_bf16(a.y) << 16));
  o.y = (int)((u32)f32_to_bf16(a.z) | ((u32)f32_to_bf16(a.w) << 16));
  o.z = (int)((u32)f32_to_bf16(b.x) | ((u32)f32_to_bf16(b.y) << 16));
  o.w = (int)((u32)f32_to_bf16(b.z) | ((u32)f32_to_bf16(b.w) << 16));
  ((int4*)Xb)[i] = o;
}

// ---------------------------------------------------------------------------
// K1: bin the directed edges. bin = dst>>7 (128 nodes/bin). Each directed
// edge stores ONE packed u32 (local_dst<<17 | src) into the bin's dense
// region -> 16 payload stores per 64B line instead of 1 (the round-4 fill_adj
// wrote 72 MB of dirty lines for 4.8 MB of payload; this is the fix).
// ---------------------------------------------------------------------------
__global__ void scatter_bins_kernel(const int* __restrict__ ra,
                                    const int* __restrict__ rb,
                                    int* __restrict__ bin_cnt,
                                    u32* __restrict__ edges,
                                    int nedges) {
  int tid = blockIdx.x * blockDim.x + threadIdx.x;
  int e0 = tid * 2;
  if (e0 >= nedges) return;
  bool has1 = (e0 + 1) < nedges;
  int2 av = ((const int2*)ra)[tid];
  int2 bv = ((const int2*)rb)[tid];
  int d0 = av.x, s0 = bv.x;
  int d1 = bv.x, s1 = av.x;
  int d2 = has1 ? av.y : 0, s2 = has1 ? bv.y : 0;
  int d3 = has1 ? bv.y : 0, s3 = has1 ? av.y : 0;
  int p0 = atomicAdd(&bin_cnt[d0 >> 7], 1);
  int p1 = atomicAdd(&bin_cnt[d1 >> 7], 1);
  int p2 = has1 ? atomicAdd(&bin_cnt[d2 >> 7], 1) : BINCAP;
  int p3 = has1 ? atomicAdd(&bin_cnt[d3 >> 7], 1) : BINCAP;
  if (p0 < BINCAP)
    edges[(size_t)(d0 >> 7) * BINCAP + p0] = ((u32)(d0 & 127) << 17) | (u32)s0;
  if (p1 < BINCAP)
    edges[(size_t)(d1 >> 7) * BINCAP + p1] = ((u32)(d1 & 127) << 17) | (u32)s1;
  if (p2 < BINCAP)
    edges[(size_t)(d2 >> 7) * BINCAP + p2] = ((u32)(d2 & 127) << 17) | (u32)s2;
  if (p3 < BINCAP)
    edges[(size_t)(d3 >> 7) * BINCAP + p3] = ((u32)(d3 & 127) << 17) | (u32)s3;
}

// ---------------------------------------------------------------------------
// K2: per-bin gather. One block per bin (128 nodes). Rebuild adjacency in
// LDS (all scattered RMW now on-chip), then gather: half-wave (32 lanes,
// uint2 = 4 bf16 feats/lane) per node, indices broadcast from LDS, 8 row
// loads in flight. fp32 accumulate, bf16 row out to Xagg (ws).
// ---------------------------------------------------------------------------
__global__ __launch_bounds__(256) void bin_gather_kernel(
    const u16* __restrict__ Xb, const u32* __restrict__ edges,
    const int* __restrict__ bin_cnt, u16* __restrict__ Xagg, int nnodes) {
  __shared__ int scnt[BINSZ];
  __shared__ int sadj[BINSZ * CAP];
  const int b = blockIdx.x;
  const int tid = threadIdx.x;
  int ne = bin_cnt[b];
  if (ne > BINCAP) ne = BINCAP;
  const u32* ep = edges + (size_t)b * BINCAP;
  if (tid < BINSZ) scnt[tid] = 0;
  __syncthreads();
  for (int i = tid; i < ne; i += 256) {
    u32 p = ep[i];
    int ld = (int)(p >> 17);
    int pos = atomicAdd(&scnt[ld], 1);
    if (pos < CAP) sadj[ld * CAP + pos] = (int)(p & 0x1FFFFu);
  }
  __syncthreads();

  const int w = tid >> 6;
  const int l = tid & 63;
  const int half = l >> 5;
  const int hl = l & 31;
  const uint2* Xv = (const uint2*)Xb;  // row = 32 uint2 (256 B)
  const int base = b * BINSZ;

#pragma unroll 1
  for (int s = 0; s < 16; ++s) {
    int nl = w * 32 + s * 2 + half;  // local node 0..127
    int node = base + nl;
    bool valid = node < nnodes;
    int n = 0;
    float a0 = 0.f, a1 = 0.f, a2 = 0.f, a3 = 0.f;
    if (valid) {
      n = scnt[nl];
      if (n > CAP) n = CAP;
      uint2 ps = Xv[(size_t)node * 32 + hl];
      a0 = __uint_as_float(ps.x << 16);
      a1 = __uint_as_float(ps.x & 0xffff0000u);
      a2 = __uint_as_float(ps.y << 16);
      a3 = __uint_as_float(ps.y & 0xffff0000u);
    }
    const int* lst = &sadj[nl * CAP];
    for (int k = 0; k < n; k += 8) {
      uint2 pv[8];
#pragma unroll
      for (int t = 0; t < 8; ++t) {
        int pos = k + t;
        int nb = lst[pos < CAP ? pos : 0];  // LDS broadcast read
        pv[t] = (pos < n) ? Xv[(size_t)nb * 32 + hl] : make_uint2(0u, 0u);
      }
#pragma unroll
      for (int t = 0; t < 8; ++t) {
        a0 += __uint_as_float(pv[t].x << 16);
        a1 += __uint_as_float(pv[t].x & 0xffff0000u);
        a2 += __uint_as_float(pv[t].y << 16);
        a3 += __uint_as_float(pv[t].y & 0xffff0000u);
      }
    }
    if (valid) {
      u32 w0 = (u32)f32_to_bf16(a0) | ((u32)f32_to_bf16(a1) << 16);
      u32 w1 = (u32)f32_to_bf16(a2) | ((u32)f32_to_bf16(a3) << 16);
      ((uint2*)Xagg)[(size_t)node * 32 + hl] = make_uint2(w0, w1);
    }
  }
}

// ---------------------------------------------------------------------------
// K3: transpose+convert weights fp32 -> bf16 (W^T layout [n][k]) into ws.
// ---------------------------------------------------------------------------
__global__ void convert_w_kernel(const float* __restrict__ Wh,
                                 const float* __restrict__ Wo,
                                 u16* __restrict__ WhT,
                                 u16* __restrict__ WoT) {
  int idx = blockIdx.x * 256 + threadIdx.x;  // 0..32767
  const float* src = (idx < 16384) ? Wh : Wo;
  u16* dst = (idx < 16384) ? WhT : WoT;
  int i = idx & 16383;
  int k = i >> 7, n = i & 127;
  dst[n * 128 + k] = f32_to_bf16(src[k * 128 + n]);
}

// ---------------------------------------------------------------------------
// K4: fused MLP via bf16 MFMA (16x16x32) -- unchanged (proven correct).
// ---------------------------------------------------------------------------
__global__ __launch_bounds__(256) void mlp_mfma_kernel(
    const u16* __restrict__ Xagg,  // [nnodes][128] bf16 (in ws)
    const u16* __restrict__ WhT,   // [128][128] bf16, [n][k]
    const u16* __restrict__ WoT,   // [128][128] bf16, [n][k]
    const float* __restrict__ bh,
    const float* __restrict__ bo,
    float* __restrict__ out, int nnodes) {
  __shared__ u16 smem[2 * 128 * 128];  // 64 KB
  u16* sA = smem;
  u16* sW = smem + 16384;

  const int tid = threadIdx.x;
  const int w = tid >> 6;
  const int l = tid & 63;
  const int l15 = l & 15;
  const int l4 = l >> 4;  // quad 0..3
  const int r0 = blockIdx.x * 128;

  // ---- stage sA (Xagg tile) and sW (Wh^T), swizzled 16B units ----
#pragma unroll
  for (int t = 0; t < 8; ++t) {
    int id = tid + t * 256;  // 0..2047 : 128 rows x 16 units
    int r = id >> 4, u = id & 15;
    int gr = r0 + r;
    if (gr >= nnodes) gr = nnodes - 1;
    *(int4*)&sA[r * 128 + ((u ^ (r & 15)) * 8)] =
        *(const int4*)&Xagg[(size_t)gr * 128 + u * 8];
    *(int4*)&sW[r * 128 + ((u ^ (r & 15)) * 8)] =
        *(const int4*)&WhT[r * 128 + u * 8];
  }

  float bhv[8], bov[8];
#pragma unroll
  for (int j = 0; j < 8; ++j) {
    bhv[j] = bh[j * 16 + l15];
    bov[j] = bo[j * 16 + l15];
  }
  __syncthreads();

  const int m0 = w * 32 + l15;       // A row, m-tile 0
  const int m1 = w * 32 + 16 + l15;  // A row, m-tile 1

  f32x4 acc[2][8];
#pragma unroll
  for (int i = 0; i < 2; ++i)
#pragma unroll
    for (int j = 0; j < 8; ++j) acc[i][j] = (f32x4){0.f, 0.f, 0.f, 0.f};

  // ---- GEMM1: hidden = Xagg @ Wh ----
#pragma unroll
  for (int c = 0; c < 4; ++c) {  // K chunks of 32
    int pu = ((c * 4 + l4) ^ l15) * 8;
    bf16x8 a0 = *(bf16x8*)&sA[m0 * 128 + pu];
    bf16x8 a1 = *(bf16x8*)&sA[m1 * 128 + pu];
#pragma unroll
    for (int j = 0; j < 8; ++j) {
      bf16x8 bfr = *(bf16x8*)&sW[(j * 16 + l15) * 128 + pu];
      acc[0][j] = __builtin_amdgcn_mfma_f32_16x16x32_bf16(a0, bfr, acc[0][j], 0, 0, 0);
      acc[1][j] = __builtin_amdgcn_mfma_f32_16x16x32_bf16(a1, bfr, acc[1][j], 0, 0, 0);
    }
  }

  __syncthreads();  // all waves done reading sW (GEMM1)

  // ---- restage sW with Wo^T ----
#pragma unroll
  for (int t = 0; t < 8; ++t) {
    int id = tid + t * 256;
    int r = id >> 4, u = id & 15;
    *(int4*)&sW[r * 128 + ((u ^ (r & 15)) * 8)] =
        *(const int4*)&WoT[r * 128 + u * 8];
  }

  // ---- bias + relu + bf16, write hidden into sA (own rows only) ----
#pragma unroll
  for (int i = 0; i < 2; ++i)
#pragma unroll
    for (int j = 0; j < 8; ++j)
#pragma unroll
      for (int r = 0; r < 4; ++r) {
        int m = w * 32 + i * 16 + l4 * 4 + r;
        float v = fmaxf(acc[i][j][r] + bhv[j], 0.f);
        int k = j * 16 + l15;
        sA[m * 128 + (((k >> 3) ^ (m & 15)) * 8) + (k & 7)] = f32_to_bf16(v);
      }
  __syncthreads();

  // ---- GEMM2: out = hidden @ Wo (reuse acc) ----
#pragma unroll
  for (int i = 0; i < 2; ++i)
#pragma unroll
    for (int j = 0; j < 8; ++j) acc[i][j] = (f32x4){0.f, 0.f, 0.f, 0.f};

#pragma unroll
  for (int c = 0; c < 4; ++c) {
    int pu = ((c * 4 + l4) ^ l15) * 8;
    bf16x8 a0 = *(bf16x8*)&sA[m0 * 128 + pu];
    bf16x8 a1 = *(bf16x8*)&sA[m1 * 128 + pu];
#pragma unroll
    for (int j = 0; j < 8; ++j) {
      bf16x8 bfr = *(bf16x8*)&sW[(j * 16 + l15) * 128 + pu];
      acc[0][j] = __builtin_amdgcn_mfma_f32_16x16x32_bf16(a0, bfr, acc[0][j], 0, 0, 0);
      acc[1][j] = __builtin_amdgcn_mfma_f32_16x16x32_bf16(a1, bfr, acc[1][j], 0, 0, 0);
    }
  }

  __syncthreads();  // everyone done with sA/sW -> reuse as fp32 out stage

  // ---- epilogue: + bo, stage in LDS, coalesced dwordx4 stores ----
  float* sOut = (float*)smem;  // 128 x 128 fp32 = 64 KB
#pragma unroll
  for (int i = 0; i < 2; ++i)
#pragma unroll
    for (int j = 0; j < 8; ++j)
#pragma unroll
      for (int r = 0; r < 4; ++r) {
        int m = w * 32 + i * 16 + l4 * 4 + r;
        sOut[m * 128 + j * 16 + l15] = acc[i][j][r] + bov[j];
      }
  __syncthreads();
#pragma unroll
  for (int t = 0; t < 16; ++t) {
    int id = tid + t * 256;  // 0..4095 float4 units
    int r = id >> 5, u4 = id & 31;
    int gr = r0 + r;
    if (gr < nnodes)
      ((float4*)out)[(size_t)gr * 32 + u4] = ((const float4*)sOut)[id];
  }
}

// ---------------------------------------------------------------------------
extern "C" void kernel_launch(void* const* d_in, const int* in_sizes, int n_in,
                              void* d_out, int out_size, void* d_ws,
                              size_t ws_size, hipStream_t stream) {
  const float* X = (const float*)d_in[0];
  const int* ra = (const int*)d_in[1];
  const int* rb = (const int*)d_in[2];
  const float* Wh = (const float*)d_in[3];
  const float* bh = (const float*)d_in[4];
  const float* Wo = (const float*)d_in[5];
  const float* bo = (const float*)d_in[6];
  float* out = (float*)d_out;

  int nnodes = in_sizes[0] / 128;
  int nedges = in_sizes[1];
  int nbins = (nnodes + BINSZ - 1) / BINSZ;

  // d_out layout during pipeline: [Xb bf16: nnodes*256 B | binned edges 5.6MB]
  // (both dead by the time mlp writes d_out).
  // ws layout: [bin_cnt @0 | WhT @16K | WoT @48K | Xagg bf16 @128K, 25.6 MB]
  // total 25.73 MB <= 26.0 MB proven available.
  u16* Xb = (u16*)d_out;
  u32* edges = (u32*)d_out + (size_t)nnodes * 64;
  int* bin_cnt = (int*)d_ws;
  u16* WhT = (u16*)((char*)d_ws + 16384);
  u16* WoT = (u16*)((char*)d_ws + 49152);
  u16* Xagg = (u16*)((char*)d_ws + 131072);

  int n8 = nnodes * 16;  // 128 feats / 8 per thread
  hipMemsetAsync(bin_cnt, 0, (size_t)nbins * 4, stream);
  convert_x_kernel<<<(n8 + 255) / 256, 256, 0, stream>>>(X, Xb, n8);
  int nthreads_fill = (nedges + 1) / 2;
  scatter_bins_kernel<<<(nthreads_fill + 255) / 256, 256, 0, stream>>>(
      ra, rb, bin_cnt, edges, nedges);
  bin_gather_kernel<<<nbins, 256, 0, stream>>>(Xb, edges, bin_cnt, Xagg,
                                               nnodes);
  convert_w_kernel<<<128, 256, 0, stream>>>(Wh, Wo, WhT, WoT);
  mlp_mfma_kernel<<<(nnodes + 127) / 128, 256, 0, stream>>>(
      Xagg, WhT, WoT, bh, bo, out, nnodes);
}

// Round 6
// 233.026 us; speedup vs baseline: 2.0170x; 2.0170x over previous
//
#include <hip/hip_runtime.h>

#define CAP 64

typedef short bf16x8 __attribute__((ext_vector_type(8)));
typedef float f32x4 __attribute__((ext_vector_type(4)));
typedef unsigned short u16;
typedef unsigned int u32;

__device__ __forceinline__ u16 f32_to_bf16(float f) {
  u32 b = __float_as_uint(f);
  b += 0x7fffu + ((b >> 16) & 1u);  // round to nearest even
  return (u16)(b >> 16);
}

// ---------------------------------------------------------------------------
// K0: X fp32 -> bf16, packed into d_out (dead until mlp overwrites it).
// ---------------------------------------------------------------------------
__global__ void convert_x_kernel(const float* __restrict__ X,
                                 u16* __restrict__ Xb, int n8) {
  int i = blockIdx.x * blockDim.x + threadIdx.x;
  if (i >= n8) return;
  float4 a = ((const float4*)X)[2 * i];
  float4 b = ((const float4*)X)[2 * i + 1];
  int4 o;
  o.x = (int)((u32)f32_to_bf16(a.x) | ((u32)f32_to_bf16(a.y) << 16));
  o.y = (int)((u32)f32_to_bf16(a.z) | ((u32)f32_to_bf16(a.w) << 16));
  o.z = (int)((u32)f32_to_bf16(b.x) | ((u32)f32_to_bf16(b.y) << 16));
  o.w = (int)((u32)f32_to_bf16(b.z) | ((u32)f32_to_bf16(b.w) << 16));
  ((int4*)Xb)[i] = o;
}

// ---------------------------------------------------------------------------
// K1: XCD-routed adjacency build. Node v's bucket (256B, line-aligned) is
// written ONLY by blocks whose filter x == (v & 7); consecutive blockIdx
// round-robin across the 8 XCDs, so filter x runs on XCD x and bucket lines
// accumulate all ~12 entries in ONE L2 before a single flush (round-4's
// 72 MB -> ~dozen MB). Filters are disjoint-exhaustive: each directed edge
// is handled exactly once regardless of the dispatch mapping (correctness
// does not depend on it; only WRITE_SIZE/speed does).
// Grid: nslices * 8 blocks; slice = blockIdx>>3 covers 512 edges.
// ---------------------------------------------------------------------------
__global__ __launch_bounds__(256) void fill_adj_xcd_kernel(
    const int* __restrict__ ra, const int* __restrict__ rb,
    int* __restrict__ cnt, int* __restrict__ adj, int nedges) {
  const int myx = blockIdx.x & 7;
  const int slice = blockIdx.x >> 3;
  int t = slice * 256 + threadIdx.x;  // int2 index
  int e0 = t * 2;
  if (e0 >= nedges) return;
  bool has1 = (e0 + 1) < nedges;
  int2 av = ((const int2*)ra)[t];
  int2 bv = ((const int2*)rb)[t];

  int d[4], s[4];
  d[0] = av.x; s[0] = bv.x;
  d[1] = bv.x; s[1] = av.x;
  d[2] = has1 ? av.y : -1; s[2] = bv.y;
  d[3] = has1 ? bv.y : -1; s[3] = av.y;
#pragma unroll
  for (int i = 0; i < 4; ++i) {
    if (d[i] >= 0 && (d[i] & 7) == myx) {
      int p = atomicAdd(&cnt[d[i]], 1);
      if (p < CAP) adj[(size_t)d[i] * CAP + p] = s[i];
    }
  }
}

// ---------------------------------------------------------------------------
// K2: gather-aggregate over bf16 X (round-4 version). TWO nodes per wave:
// half-wave (32 lanes) per node, uint2 (4 bf16 feats) per lane. Indices
// loaded coalesced and broadcast via __shfl; 8 row loads in flight. fp32
// accumulate; result written as a bf16 row into the node's own adj bucket
// (fully consumed before the store; buckets disjoint -> race-free).
// ---------------------------------------------------------------------------
__global__ void gather_agg_kernel(const u16* __restrict__ Xb,
                                  const int* __restrict__ cnt,
                                  int* __restrict__ adj,
                                  int nnodes) {
  int gid = blockIdx.x * blockDim.x + threadIdx.x;
  int wid = gid >> 6;
  int l = gid & 63;
  int half = l >> 5;
  int hl = l & 31;
  int node = wid * 2 + half;
  if (node >= nnodes) return;
  const uint2* Xv = (const uint2*)Xb;  // row = 32 uint2 (256 B)
  const int* lst = adj + (size_t)node * CAP;
  int idx0 = lst[hl];       // positions 0..31
  int idx1 = lst[hl + 32];  // positions 32..63
  int n = cnt[node];
  if (n > CAP) n = CAP;
  uint2 ps = Xv[(size_t)node * 32 + hl];
  float a0 = __uint_as_float(ps.x << 16);
  float a1 = __uint_as_float(ps.x & 0xffff0000u);
  float a2 = __uint_as_float(ps.y << 16);
  float a3 = __uint_as_float(ps.y & 0xffff0000u);
  const int base = half << 5;
  for (int k = 0; k < n; k += 8) {
    uint2 pv[8];
#pragma unroll
    for (int t = 0; t < 8; ++t) {
      int pos = k + t;
      int sel = (pos < 32) ? idx0 : idx1;
      int nb = __shfl(sel, base + (pos & 31));
      pv[t] = (pos < n) ? Xv[(size_t)nb * 32 + hl] : make_uint2(0u, 0u);
    }
#pragma unroll
    for (int t = 0; t < 8; ++t) {
      a0 += __uint_as_float(pv[t].x << 16);
      a1 += __uint_as_float(pv[t].x & 0xffff0000u);
      a2 += __uint_as_float(pv[t].y << 16);
      a3 += __uint_as_float(pv[t].y & 0xffff0000u);
    }
  }
  u32 w0 = (u32)f32_to_bf16(a0) | ((u32)f32_to_bf16(a1) << 16);
  u32 w1 = (u32)f32_to_bf16(a2) | ((u32)f32_to_bf16(a3) << 16);
  ((uint2*)adj)[(size_t)node * 32 + hl] = make_uint2(w0, w1);
}

// ---------------------------------------------------------------------------
// K3: transpose+convert weights fp32 -> bf16 (W^T layout [n][k]) into the
// dead `cnt` region (runs after gather).
// ---------------------------------------------------------------------------
__global__ void convert_w_kernel(const float* __restrict__ Wh,
                                 const float* __restrict__ Wo,
                                 u16* __restrict__ WhT,
                                 u16* __restrict__ WoT) {
  int idx = blockIdx.x * 256 + threadIdx.x;  // 0..32767
  const float* src = (idx < 16384) ? Wh : Wo;
  u16* dst = (idx < 16384) ? WhT : WoT;
  int i = idx & 16383;
  int k = i >> 7, n = i & 127;
  dst[n * 128 + k] = f32_to_bf16(src[k * 128 + n]);
}

// ---------------------------------------------------------------------------
// K4: fused MLP via bf16 MFMA (16x16x32) -- unchanged (proven correct).
// ---------------------------------------------------------------------------
__global__ __launch_bounds__(256) void mlp_mfma_kernel(
    const u16* __restrict__ Xagg,  // [nnodes][128] bf16 (lives in adj region)
    const u16* __restrict__ WhT,   // [128][128] bf16, [n][k]
    const u16* __restrict__ WoT,   // [128][128] bf16, [n][k]
    const float* __restrict__ bh,
    const float* __restrict__ bo,
    float* __restrict__ out, int nnodes) {
  __shared__ u16 smem[2 * 128 * 128];  // 64 KB
  u16* sA = smem;
  u16* sW = smem + 16384;

  const int tid = threadIdx.x;
  const int w = tid >> 6;
  const int l = tid & 63;
  const int l15 = l & 15;
  const int l4 = l >> 4;  // quad 0..3
  const int r0 = blockIdx.x * 128;

  // ---- stage sA (Xagg tile) and sW (Wh^T), swizzled 16B units ----
#pragma unroll
  for (int t = 0; t < 8; ++t) {
    int id = tid + t * 256;  // 0..2047 : 128 rows x 16 units
    int r = id >> 4, u = id & 15;
    int gr = r0 + r;
    if (gr >= nnodes) gr = nnodes - 1;
    *(int4*)&sA[r * 128 + ((u ^ (r & 15)) * 8)] =
        *(const int4*)&Xagg[(size_t)gr * 128 + u * 8];
    *(int4*)&sW[r * 128 + ((u ^ (r & 15)) * 8)] =
        *(const int4*)&WhT[r * 128 + u * 8];
  }

  float bhv[8], bov[8];
#pragma unroll
  for (int j = 0; j < 8; ++j) {
    bhv[j] = bh[j * 16 + l15];
    bov[j] = bo[j * 16 + l15];
  }
  __syncthreads();

  const int m0 = w * 32 + l15;       // A row, m-tile 0
  const int m1 = w * 32 + 16 + l15;  // A row, m-tile 1

  f32x4 acc[2][8];
#pragma unroll
  for (int i = 0; i < 2; ++i)
#pragma unroll
    for (int j = 0; j < 8; ++j) acc[i][j] = (f32x4){0.f, 0.f, 0.f, 0.f};

  // ---- GEMM1: hidden = Xagg @ Wh ----
#pragma unroll
  for (int c = 0; c < 4; ++c) {  // K chunks of 32
    int pu = ((c * 4 + l4) ^ l15) * 8;
    bf16x8 a0 = *(bf16x8*)&sA[m0 * 128 + pu];
    bf16x8 a1 = *(bf16x8*)&sA[m1 * 128 + pu];
#pragma unroll
    for (int j = 0; j < 8; ++j) {
      bf16x8 bfr = *(bf16x8*)&sW[(j * 16 + l15) * 128 + pu];
      acc[0][j] = __builtin_amdgcn_mfma_f32_16x16x32_bf16(a0, bfr, acc[0][j], 0, 0, 0);
      acc[1][j] = __builtin_amdgcn_mfma_f32_16x16x32_bf16(a1, bfr, acc[1][j], 0, 0, 0);
    }
  }

  __syncthreads();  // all waves done reading sW (GEMM1)

  // ---- restage sW with Wo^T ----
#pragma unroll
  for (int t = 0; t < 8; ++t) {
    int id = tid + t * 256;
    int r = id >> 4, u = id & 15;
    *(int4*)&sW[r * 128 + ((u ^ (r & 15)) * 8)] =
        *(const int4*)&WoT[r * 128 + u * 8];
  }

  // ---- bias + relu + bf16, write hidden into sA (own rows only) ----
#pragma unroll
  for (int i = 0; i < 2; ++i)
#pragma unroll
    for (int j = 0; j < 8; ++j)
#pragma unroll
      for (int r = 0; r < 4; ++r) {
        int m = w * 32 + i * 16 + l4 * 4 + r;
        float v = fmaxf(acc[i][j][r] + bhv[j], 0.f);
        int k = j * 16 + l15;
        sA[m * 128 + (((k >> 3) ^ (m & 15)) * 8) + (k & 7)] = f32_to_bf16(v);
      }
  __syncthreads();

  // ---- GEMM2: out = hidden @ Wo (reuse acc) ----
#pragma unroll
  for (int i = 0; i < 2; ++i)
#pragma unroll
    for (int j = 0; j < 8; ++j) acc[i][j] = (f32x4){0.f, 0.f, 0.f, 0.f};

#pragma unroll
  for (int c = 0; c < 4; ++c) {
    int pu = ((c * 4 + l4) ^ l15) * 8;
    bf16x8 a0 = *(bf16x8*)&sA[m0 * 128 + pu];
    bf16x8 a1 = *(bf16x8*)&sA[m1 * 128 + pu];
#pragma unroll
    for (int j = 0; j < 8; ++j) {
      bf16x8 bfr = *(bf16x8*)&sW[(j * 16 + l15) * 128 + pu];
      acc[0][j] = __builtin_amdgcn_mfma_f32_16x16x32_bf16(a0, bfr, acc[0][j], 0, 0, 0);
      acc[1][j] = __builtin_amdgcn_mfma_f32_16x16x32_bf16(a1, bfr, acc[1][j], 0, 0, 0);
    }
  }

  __syncthreads();  // everyone done with sA/sW -> reuse as fp32 out stage

  // ---- epilogue: + bo, stage in LDS, coalesced dwordx4 stores ----
  float* sOut = (float*)smem;  // 128 x 128 fp32 = 64 KB
#pragma unroll
  for (int i = 0; i < 2; ++i)
#pragma unroll
    for (int j = 0; j < 8; ++j)
#pragma unroll
      for (int r = 0; r < 4; ++r) {
        int m = w * 32 + i * 16 + l4 * 4 + r;
        sOut[m * 128 + j * 16 + l15] = acc[i][j][r] + bov[j];
      }
  __syncthreads();
#pragma unroll
  for (int t = 0; t < 16; ++t) {
    int id = tid + t * 256;  // 0..4095 float4 units
    int r = id >> 5, u4 = id & 31;
    int gr = r0 + r;
    if (gr < nnodes)
      ((float4*)out)[(size_t)gr * 32 + u4] = ((const float4*)sOut)[id];
  }
}

// ---------------------------------------------------------------------------
extern "C" void kernel_launch(void* const* d_in, const int* in_sizes, int n_in,
                              void* d_out, int out_size, void* d_ws,
                              size_t ws_size, hipStream_t stream) {
  const float* X = (const float*)d_in[0];
  const int* ra = (const int*)d_in[1];
  const int* rb = (const int*)d_in[2];
  const float* Wh = (const float*)d_in[3];
  const float* bh = (const float*)d_in[4];
  const float* Wo = (const float*)d_in[5];
  const float* bo = (const float*)d_in[6];
  float* out = (float*)d_out;

  int nnodes = in_sizes[0] / 128;
  int nedges = in_sizes[1];

  // ws layout: [cnt: nnodes ints | adj: nnodes*CAP ints] (26.0 MB, proven).
  // Xb (bf16 X) lives in d_out until mlp overwrites it (gather consumed it).
  // After gather: adj holds Xagg bf16 rows; cnt region dead -> WhT/WoT.
  int* cnt = (int*)d_ws;
  int* adj = cnt + nnodes;
  u16* WhT = (u16*)d_ws;
  u16* WoT = WhT + 16384;
  u16* Xb = (u16*)d_out;

  int n8 = nnodes * 16;  // 128 feats / 8 per thread
  hipMemsetAsync(cnt, 0, (size_t)nnodes * 4, stream);
  convert_x_kernel<<<(n8 + 255) / 256, 256, 0, stream>>>(X, Xb, n8);
  int nslices = ((nedges + 1) / 2 + 255) / 256;  // 512 edges per slice
  fill_adj_xcd_kernel<<<nslices * 8, 256, 0, stream>>>(ra, rb, cnt, adj,
                                                       nedges);
  int nwaves = (nnodes + 1) / 2;
  gather_agg_kernel<<<(nwaves * 64 + 255) / 256, 256, 0, stream>>>(Xb, cnt,
                                                                   adj, nnodes);
  convert_w_kernel<<<128, 256, 0, stream>>>(Wh, Wo, WhT, WoT);
  mlp_mfma_kernel<<<(nnodes + 127) / 128, 256, 0, stream>>>(
      (const u16*)adj, WhT, WoT, bh, bo, out, nnodes);
}